// Round 7
// baseline (753.683 us; speedup 1.0000x reference)
//
#include <hip/hip_runtime.h>
#include <math.h>

#define B_  1024
#define S_  256
#define H_  512
#define E_  64
#define R_  32
#define L_  9
#define EPS_ 1e-6f
#define TB  8    // b-tile for MLP kernel

// ---------------------------------------------------------------------------
// Kernel 1: fused 2-layer MLP for the 4 live modules (m=0 -> e[0], m=1..3 -> r[0..2])
// Layer-1: thread owns 4 consecutive h-cols (float4 W1 loads, 1 KB/wave) and
//          4 b-rows; 4 independent float4 loads in flight per s4 iteration.
// Layer-2: unchanged (small).
// grid (B/TB, 4), block 256
// ---------------------------------------------------------------------------
__global__ __launch_bounds__(256) void mlp_kernel(
    const float* __restrict__ x,     // [B,S]
    const float* __restrict__ eW1, const float* __restrict__ eb1,
    const float* __restrict__ eW2, const float* __restrict__ eb2,
    const float* __restrict__ rW1, const float* __restrict__ rb1,
    const float* __restrict__ rW2, const float* __restrict__ rb2,
    float* __restrict__ e0_out,      // [B,E]
    float* __restrict__ r_out)       // [3,B,R]
{
    __shared__ __align__(16) float xs[TB][S_];   // 8 KB
    __shared__ __align__(16) float hs[TB][H_];   // 16 KB
    const int t  = threadIdx.x;
    const int b0 = blockIdx.x * TB;
    const int m  = blockIdx.y;       // 0 = e0, 1..3 = r0..r2

    {
        const float4* x4 = (const float4*)(x + (size_t)b0 * S_);
        float4* xs4 = (float4*)&xs[0][0];
        xs4[t]       = x4[t];
        xs4[t + 256] = x4[t + 256];
    }
    __syncthreads();

    const float* W1 = (m == 0) ? eW1 : (rW1 + (size_t)(m - 1) * S_ * H_);
    const float* b1 = (m == 0) ? eb1 : (rb1 + (size_t)(m - 1) * H_);

    const int c4   = t & 127;        // float4 column group: h = 4*c4 .. 4*c4+3
    const int half = t >> 7;         // bb half: 0 -> bb 0..3, 1 -> bb 4..7

    float4 acc[4];
    #pragma unroll
    for (int q = 0; q < 4; ++q) acc[q] = (float4){0, 0, 0, 0};

    for (int s4 = 0; s4 < S_ / 4; ++s4) {
        const float4* Wrow = (const float4*)(W1 + (size_t)(4 * s4) * H_);
        // 4 independent float4 loads (1 KB per wave-load, L2-resident)
        float4 w0 = Wrow[c4];
        float4 w1 = Wrow[128 + c4];
        float4 w2 = Wrow[256 + c4];
        float4 w3 = Wrow[384 + c4];
        #pragma unroll
        for (int q = 0; q < 4; ++q) {
            float4 xv = ((const float4*)&xs[half * 4 + q][0])[s4];   // ds_read_b128
            acc[q].x = fmaf(xv.x, w0.x, acc[q].x); acc[q].y = fmaf(xv.x, w0.y, acc[q].y);
            acc[q].z = fmaf(xv.x, w0.z, acc[q].z); acc[q].w = fmaf(xv.x, w0.w, acc[q].w);
            acc[q].x = fmaf(xv.y, w1.x, acc[q].x); acc[q].y = fmaf(xv.y, w1.y, acc[q].y);
            acc[q].z = fmaf(xv.y, w1.z, acc[q].z); acc[q].w = fmaf(xv.y, w1.w, acc[q].w);
            acc[q].x = fmaf(xv.z, w2.x, acc[q].x); acc[q].y = fmaf(xv.z, w2.y, acc[q].y);
            acc[q].z = fmaf(xv.z, w2.z, acc[q].z); acc[q].w = fmaf(xv.z, w2.w, acc[q].w);
            acc[q].x = fmaf(xv.w, w3.x, acc[q].x); acc[q].y = fmaf(xv.w, w3.y, acc[q].y);
            acc[q].z = fmaf(xv.w, w3.z, acc[q].z); acc[q].w = fmaf(xv.w, w3.w, acc[q].w);
        }
    }
    {
        float4 bias4 = ((const float4*)b1)[c4];
        #pragma unroll
        for (int q = 0; q < 4; ++q) {
            float4 hv;
            hv.x = tanhf(acc[q].x + bias4.x);
            hv.y = tanhf(acc[q].y + bias4.y);
            hv.z = tanhf(acc[q].z + bias4.z);
            hv.w = tanhf(acc[q].w + bias4.w);
            ((float4*)&hs[half * 4 + q][0])[c4] = hv;
        }
    }
    __syncthreads();

    if (m == 0) {
        const float* W2 = eW2;
        const float* b2 = eb2;
        int o  = t & 63;
        int bq = t >> 6;                     // 0..3
        #pragma unroll
        for (int i = 0; i < TB / 4; ++i) {
            int bb = bq + i * 4;
            float a0 = 0.f, a1 = 0.f, a2 = 0.f, a3 = 0.f;
            #pragma unroll 4
            for (int j = 0; j < H_; j += 4) {
                float4 hv = ((const float4*)&hs[bb][0])[j >> 2];
                a0 = fmaf(hv.x, W2[(size_t)(j + 0) * E_ + o], a0);
                a1 = fmaf(hv.y, W2[(size_t)(j + 1) * E_ + o], a1);
                a2 = fmaf(hv.z, W2[(size_t)(j + 2) * E_ + o], a2);
                a3 = fmaf(hv.w, W2[(size_t)(j + 3) * E_ + o], a3);
            }
            e0_out[(size_t)(b0 + bb) * E_ + o] = b2[o] + ((a0 + a1) + (a2 + a3));
        }
    } else {
        const float* W2 = rW2 + (size_t)(m - 1) * H_ * R_;
        const float* b2 = rb2 + (size_t)(m - 1) * R_;
        int o  = t & 31;
        int bb = t >> 5;                     // 0..7 == TB
        float a0 = 0.f, a1 = 0.f, a2 = 0.f, a3 = 0.f;
        #pragma unroll 4
        for (int j = 0; j < H_; j += 4) {
            float4 hv = ((const float4*)&hs[bb][0])[j >> 2];
            a0 = fmaf(hv.x, W2[(size_t)(j + 0) * R_ + o], a0);
            a1 = fmaf(hv.y, W2[(size_t)(j + 1) * R_ + o], a1);
            a2 = fmaf(hv.z, W2[(size_t)(j + 2) * R_ + o], a2);
            a3 = fmaf(hv.w, W2[(size_t)(j + 3) * R_ + o], a3);
        }
        r_out[((size_t)(m - 1) * B_ + (b0 + bb)) * R_ + o] = b2[o] + ((a0 + a1) + (a2 + a3));
    }
}

// ---------------------------------------------------------------------------
// Kernel 2: fused per-b TPR chain, single pass over tpr[b].
//  Phase M: per-wave contiguous 128 KB stream (16 e-rows), with EXPLICIT
//    2-row register double-buffer: row el+1's 8 loads are issued BEFORE
//    row el is consumed -> 8 loads continuously outstanding (no burst
//    duty-cycle gaps). Named buffers bA/bB = static indexing (no scratch).
//  Phase S: wave 0 only, unchanged.
//  ~115 VGPR, 34 KB LDS -> 4 blocks/CU.
// ---------------------------------------------------------------------------
__global__ __launch_bounds__(256) void tpr_kernel(
    const float* __restrict__ tpr,   // [B,E,R,E]
    const float* __restrict__ e0,    // [B,E]
    const float* __restrict__ rws,   // [3,B,R]
    const float* __restrict__ ln_g,  // [3,E]
    const float* __restrict__ ln_b,  // [3,E]
    const float* __restrict__ Z,     // [E,L]
    float* __restrict__ out)         // [B,L]
{
    __shared__ __align__(16) float M[2][E_][E_];     // 32 KB  (M1, M2)
    __shared__ __align__(16) float red[4][E_];       // 1 KB   (t0 partials, per wave)
    __shared__ float xcur[E_];
    __shared__ float ssum_sh[E_];
    __shared__ float rsh[3][R_];
    __shared__ float e0sh[E_];

    const int t = threadIdx.x;
    const int b = blockIdx.x;

    if (t < 96) { int k = t >> 5, j = t & 31; rsh[k][j] = rws[((size_t)k * B_ + b) * R_ + j]; }
    if (t < E_) e0sh[t] = e0[(size_t)b * E_ + t];
    __syncthreads();

    // ---- Phase M: contiguous per-wave stream, 2-row pipeline ----
    const int w  = t >> 6;       // wave 0..3: owns e in [w*16, w*16+16)
    const int j  = t & 63;       // lane
    const int jh = j >> 4;       // r-subgroup 0..3
    const float4* base = (const float4*)(tpr + (size_t)b * E_ * R_ * E_) + w * 8192;

    // preload this lane's r-weights: r = it*4 + jh, it = 0..7
    float wk0[8], wk1[8], wk2[8];
    #pragma unroll
    for (int it = 0; it < 8; ++it) {
        int r = it * 4 + jh;
        wk0[it] = rsh[0][r]; wk1[it] = rsh[1][r]; wk2[it] = rsh[2][r];
    }

#define LOADROW(BUF, EL)                                                   \
    {                                                                      \
        _Pragma("unroll")                                                  \
        for (int it = 0; it < 8; ++it)                                     \
            BUF[it] = base[(EL) * 512 + it * 64 + j];                      \
    }

#define CONSUME(BUF, EL)                                                   \
    {                                                                      \
        float4 a0 = {0,0,0,0}, a1 = {0,0,0,0}, a2 = {0,0,0,0};             \
        _Pragma("unroll")                                                  \
        for (int it = 0; it < 8; ++it) {                                   \
            float4 v = BUF[it];                                            \
            float w0 = wk0[it], w1 = wk1[it], w2 = wk2[it];                 \
            a0.x = fmaf(w0, v.x, a0.x); a0.y = fmaf(w0, v.y, a0.y);        \
            a0.z = fmaf(w0, v.z, a0.z); a0.w = fmaf(w0, v.w, a0.w);        \
            a1.x = fmaf(w1, v.x, a1.x); a1.y = fmaf(w1, v.y, a1.y);        \
            a1.z = fmaf(w1, v.z, a1.z); a1.w = fmaf(w1, v.w, a1.w);        \
            a2.x = fmaf(w2, v.x, a2.x); a2.y = fmaf(w2, v.y, a2.y);        \
            a2.z = fmaf(w2, v.z, a2.z); a2.w = fmaf(w2, v.w, a2.w);        \
        }                                                                  \
        _Pragma("unroll")                                                  \
        for (int st = 16; st <= 32; st <<= 1) {                            \
            a0.x += __shfl_xor(a0.x, st); a0.y += __shfl_xor(a0.y, st);    \
            a0.z += __shfl_xor(a0.z, st); a0.w += __shfl_xor(a0.w, st);    \
            a1.x += __shfl_xor(a1.x, st); a1.y += __shfl_xor(a1.y, st);    \
            a1.z += __shfl_xor(a1.z, st); a1.w += __shfl_xor(a1.w, st);    \
            a2.x += __shfl_xor(a2.x, st); a2.y += __shfl_xor(a2.y, st);    \
            a2.z += __shfl_xor(a2.z, st); a2.w += __shfl_xor(a2.w, st);    \
        }                                                                  \
        const int e = w * 16 + (EL);                                       \
        if (j < 16) {                                                      \
            ((float4*)&M[0][e][0])[j] = a1;                                \
            ((float4*)&M[1][e][0])[j] = a2;                                \
        }                                                                  \
        float ev = e0sh[e];                                                \
        t0p.x = fmaf(ev, a0.x, t0p.x); t0p.y = fmaf(ev, a0.y, t0p.y);      \
        t0p.z = fmaf(ev, a0.z, t0p.z); t0p.w = fmaf(ev, a0.w, t0p.w);      \
    }

    float4 t0p = {0, 0, 0, 0};
    float4 bA[8], bB[8];
    LOADROW(bA, 0);
    for (int el = 0; el < 16; el += 2) {
        LOADROW(bB, el + 1);          // next row in flight while consuming bA
        CONSUME(bA, el);
        if (el + 2 < 16) LOADROW(bA, el + 2);   // keep pipe full
        CONSUME(bB, el + 1);
    }
#undef LOADROW
#undef CONSUME

    if (j < 16) ((float4*)&red[w][0])[j] = t0p;
    __syncthreads();

    // ---- Phase S: wave 0 only, no barriers (in-wave LDS ordering suffices) ----
    if (t < E_) {
        const int f = t;
        float acc = 0.0f;
        #pragma unroll
        for (int g = 0; g < 4; ++g) acc += red[g][f];

        float ssum = 0.0f;
        #pragma unroll
        for (int k = 0; k < 3; ++k) {
            float s = acc;
            #pragma unroll
            for (int off = 32; off >= 1; off >>= 1) s += __shfl_xor(s, off, 64);
            float mu = s * (1.0f / 64.0f);
            float d = acc - mu;
            float vs = d * d;
            #pragma unroll
            for (int off = 32; off >= 1; off >>= 1) vs += __shfl_xor(vs, off, 64);
            float var = vs * (1.0f / 64.0f);
            float iv = ln_g[k * E_ + f] * d * rsqrtf(var + EPS_) + ln_b[k * E_ + f];
            ssum += iv;
            if (k < 2) {
                xcur[f] = iv;
                float n0 = 0.f, n1 = 0.f, n2 = 0.f, n3 = 0.f;
                #pragma unroll 4
                for (int e = 0; e < E_; e += 4) {
                    n0 = fmaf(xcur[e + 0], M[k][e + 0][f], n0);
                    n1 = fmaf(xcur[e + 1], M[k][e + 1][f], n1);
                    n2 = fmaf(xcur[e + 2], M[k][e + 2][f], n2);
                    n3 = fmaf(xcur[e + 3], M[k][e + 3][f], n3);
                }
                acc = (n0 + n1) + (n2 + n3);
            }
        }
        ssum_sh[f] = ssum;

        if (t < L_) {
            float o = 0.0f;
            #pragma unroll
            for (int f2 = 0; f2 < E_; ++f2)
                o = fmaf(ssum_sh[f2], Z[f2 * L_ + t], o);
            out[(size_t)b * L_ + t] = o;
        }
    }
}

// ---------------------------------------------------------------------------
extern "C" void kernel_launch(void* const* d_in, const int* in_sizes, int n_in,
                              void* d_out, int out_size, void* d_ws, size_t ws_size,
                              hipStream_t stream) {
    const float* x    = (const float*)d_in[0];
    const float* tpr  = (const float*)d_in[1];
    const float* eW1  = (const float*)d_in[2];
    const float* eb1  = (const float*)d_in[3];
    const float* eW2  = (const float*)d_in[4];
    const float* eb2  = (const float*)d_in[5];
    const float* rW1  = (const float*)d_in[6];
    const float* rb1  = (const float*)d_in[7];
    const float* rW2  = (const float*)d_in[8];
    const float* rb2  = (const float*)d_in[9];
    const float* ln_g = (const float*)d_in[10];
    const float* ln_b = (const float*)d_in[11];
    const float* Z    = (const float*)d_in[12];
    float* out = (float*)d_out;

    float* e0_ws = (float*)d_ws;             // B*E floats
    float* r_ws  = e0_ws + (size_t)B_ * E_;  // 3*B*R floats

    dim3 g1(B_ / TB, 4);
    mlp_kernel<<<g1, 256, 0, stream>>>(x, eW1, eb1, eW2, eb2,
                                       rW1, rb1, rW2, rb2, e0_ws, r_ws);
    tpr_kernel<<<B_, 256, 0, stream>>>(tpr, e0_ws, r_ws, ln_g, ln_b, Z, out);
}